// Round 8
// baseline (59.687 us; speedup 1.0000x reference)
//
#include <hip/hip_runtime.h>
#include <math.h>

#define NB   16
#define NQ   4096
#define NTGT 128
#define CELEMS (NB * NQ * NTGT)

#define BT  512
#define NW  (BT / 64)
#define CPT 8              // columns per thread in lsa (NQ / BT), strided ownership
#define NBLK 128           // cost blocks per batch == rowkey slots per batch

typedef unsigned long long u64;

// ---------------- cost matrix + per-row (target) min/argmin ----------------
// Grid 2048 x 256. Each thread handles 4 q's x 4 t's (16 cells); float4 loads
// and stores fully coalesced. Block covers 32 q x 128 t; per-row key
// (cost_bits<<32 | q, u64-min == min cost then lowest q) is reduced in LDS,
// then PLAIN-stored to the block's own slot rowkey2[b][blk][t].
__global__ __launch_bounds__(256) void cost_kernel(
    const float* __restrict__ outputs,
    const float* __restrict__ targets,
    float* __restrict__ C,
    u64*   __restrict__ rowkey2)      // [NB][NBLK][NTGT]
{
    __shared__ u64 part[8][NTGT];     // 8 KB
    const int tid  = threadIdx.x;
    const int idx0 = blockIdx.x * 1024 + tid;    // quad-cell base
    const int t4   = tid & 31;
    const int qloc = tid >> 5;
    const int b    = blockIdx.x >> 7;            // 128 blocks per batch
    const int blk  = blockIdx.x & (NBLK - 1);

    const float4* tg = reinterpret_cast<const float4*>(targets) + (b << 7) + (t4 << 2);
    float4 g[4];
    #pragma unroll
    for (int f = 0; f < 4; ++f) g[f] = tg[f];

    u64 keymin[4] = {~0ull, ~0ull, ~0ull, ~0ull};

    #pragma unroll
    for (int e = 0; e < 4; ++e) {
        int idx = idx0 + 256 * e;
        int bq  = idx >> 5;
        float4 o = reinterpret_cast<const float4*>(outputs)[bq];
        u64 q = (u64)(unsigned)(bq & (NQ - 1));
        float r[4];
        #pragma unroll
        for (int f = 0; f < 4; ++f) {
            float4 gg = g[f];
            r[f] = (fabsf(o.x - gg.x) + fabsf(o.y - gg.y)) +
                   (fabsf(o.z - gg.z) + fabsf(o.w - gg.w));
            u64 key = (((u64)__float_as_uint(r[f])) << 32) | q;
            if (key < keymin[f]) keymin[f] = key;
        }
        reinterpret_cast<float4*>(C)[idx] = make_float4(r[0], r[1], r[2], r[3]);
    }

    #pragma unroll
    for (int f = 0; f < 4; ++f) part[qloc][(t4 << 2) + f] = keymin[f];
    __syncthreads();

    if (tid < NTGT) {
        u64 k = part[0][tid];
        #pragma unroll
        for (int qq = 1; qq < 8; ++qq) { u64 ov = part[qq][tid]; if (ov < k) k = ov; }
        rowkey2[(((size_t)b * NBLK) + blk) * NTGT + tid] = k;
    }
}

// ---------------- LSA kernel: row-reduction init + rare augmentation ----------
// One block per batch, transposed problem: 128 rows (targets) x 4096 cols
// (queries). u[i] = rowmin[i], v = 0 (dual feasible); greedy claim of tight
// edges via LDS atomicMin; leftover rows run exact f64 shortest-augmenting-
// path (scipy-equivalent) from these duals -> provably optimal matching.
// All column state in LDS with STRIDED ownership (thread t owns columns
// t, t+512, ...): conflict-free LDS access, coalesced global reads, no big
// register arrays (avoids scratch demotion).
__global__ __launch_bounds__(BT, 1) void lsa_kernel(
    const float* __restrict__ outputs,
    const float* __restrict__ targets,
    const u64*   __restrict__ rowkey2,
    float* __restrict__ row_out,   // [NB, NTGT] as float
    float* __restrict__ col_out)   // [NB, NTGT] as float
{
    __shared__ double v_[NQ];               // 32 KB
    __shared__ double shortest_[NQ];        // 32 KB
    __shared__ unsigned col_tmp[NQ];        // 16 KB (claim arbitration)
    __shared__ short  row4col_[NQ];         // 8 KB
    __shared__ unsigned char path_[NQ];     // 4 KB
    __shared__ float4 tgt_[NTGT];
    __shared__ double u_[NTGT];
    __shared__ int    rowarg_[NTGT];
    __shared__ u64    red2_[4][NTGT];
    __shared__ short  col4row_[NTGT];
    __shared__ short  left_[NTGT];
    __shared__ int    sc_j[NTGT];
    __shared__ double red_val[NW];
    __shared__ int    red_idx[NW];
    __shared__ u64    bmask[2];
    __shared__ int    nleft_;

    const int tid = threadIdx.x;
    const int b   = blockIdx.x;
    const float4* outq = reinterpret_cast<const float4*>(outputs) + b * NQ;

    // init column state
    #pragma unroll
    for (int kk = 0; kk < CPT; ++kk) {
        int k = tid + BT * kk;
        v_[k] = 0.0;
        row4col_[k] = -1;
        col_tmp[k] = 0xFFFFFFFFu;
    }

    // reduce the 128 slot keys per row (coalesced: consecutive lanes -> consecutive t)
    {
        const int t = tid & 127, s = tid >> 7;            // 4 slices x 32 slots
        const u64* rk = rowkey2 + (size_t)b * NBLK * NTGT;
        u64 k = ~0ull;
        #pragma unroll
        for (int gg = 0; gg < NBLK / 4; ++gg) {
            u64 ov = rk[(s * (NBLK / 4) + gg) * NTGT + t];
            if (ov < k) k = ov;
        }
        red2_[s][t] = k;
    }
    __syncthreads();

    if (tid < NTGT) {
        u64 key = red2_[0][tid];
        #pragma unroll
        for (int s = 1; s < 4; ++s) { u64 ov = red2_[s][tid]; if (ov < key) key = ov; }
        u_[tid] = (double)__uint_as_float((unsigned)(key >> 32));
        rowarg_[tid] = (int)(key & 0xffffffffu);
        tgt_[tid] = reinterpret_cast<const float4*>(targets)[b * NTGT + tid];
    }
    __syncthreads();

    // greedy claim of tight edges: lowest row wins each contested column
    if (tid < NTGT) atomicMin(&col_tmp[rowarg_[tid]], (unsigned)tid);
    __syncthreads();

    bool un = false;
    if (tid < NTGT) {
        int j = rowarg_[tid];
        bool won = (col_tmp[j] == (unsigned)tid);
        col4row_[tid] = won ? (short)j : (short)-1;
        if (won) row4col_[j] = (short)tid;   // winners have distinct j
        un = !won;
    }
    // ballot-compact the unmatched rows (ascending tid order)
    {
        u64 m = __ballot(un);
        if ((tid & 63) == 0 && (tid >> 6) < 2) bmask[tid >> 6] = m;
    }
    __syncthreads();
    if (un) {
        int lane = tid & 63, w = tid >> 6;
        int r = __popcll(bmask[w] & ((1ull << lane) - 1)) + (w ? __popcll(bmask[0]) : 0);
        left_[r] = (short)tid;
    }
    if (tid == 0) nleft_ = __popcll(bmask[0]) + __popcll(bmask[1]);
    __syncthreads();
    const int nleft = nleft_;

    // ---- exact shortest-augmenting-path for leftover rows (rare) ----
    for (int li = 0; li < nleft; ++li) {
        const int cur = left_[li];
        #pragma unroll
        for (int kk = 0; kk < CPT; ++kk) shortest_[tid + BT * kk] = (double)INFINITY;
        unsigned rem  = 0xFFu;
        int    i      = cur;
        double minv   = 0.0;
        int    fj     = -1;
        int    Lns    = 0;
        __syncthreads();   // shortest_ init + prior row's tid0 updates visible

        while (true) {
            const double ui = u_[i];
            const float4 g  = tgt_[i];

            double bv = (double)INFINITY;
            int    bi = 0x7fffffff;

            #pragma unroll
            for (int kk = 0; kk < CPT; ++kk) {
                if (rem & (1u << kk)) {
                    int k = tid + BT * kk;
                    float4 oo = outq[k];
                    float  c  = (fabsf(oo.x - g.x) + fabsf(oo.y - g.y)) +
                                (fabsf(oo.z - g.z) + fabsf(oo.w - g.w));
                    double cand = ((minv + (double)c) - ui) - v_[k];
                    if (cand < shortest_[k]) { shortest_[k] = cand; path_[k] = (unsigned char)i; }
                    double s = shortest_[k];
                    if (s < bv) { bv = s; bi = k; }   // k ascends per thread -> lowest col on tie
                }
            }

            // wave reduce with explicit (value, lowest-index) tie-break
            for (int off = 32; off > 0; off >>= 1) {
                double ov = __shfl_down(bv, off);
                int    oi = __shfl_down(bi, off);
                if (ov < bv || (ov == bv && oi < bi)) { bv = ov; bi = oi; }
            }
            if ((tid & 63) == 0) { red_val[tid >> 6] = bv; red_idx[tid >> 6] = bi; }
            __syncthreads();

            double fv = red_val[0];
            int    jj = red_idx[0];
            #pragma unroll
            for (int w = 1; w < NW; ++w) {
                double ov = red_val[w];
                int    oi = red_idx[w];
                if (ov < fv || (ov == fv && oi < jj)) { fv = ov; jj = oi; }
            }
            __syncthreads();   // protects red slot reuse next iteration

            fj   = jj;
            minv = fv;

            if ((fj & (BT - 1)) == tid) rem &= ~(1u << (fj >> 9));   // owner: drop from remaining

            int r = row4col_[fj];
            if (r < 0) break;                 // sink found
            if (tid == 0) sc_j[Lns] = fj;
            Lns++;
            i = r;
        }

        // ---- row end: duals + augment (tid0; reference op order) ----
        const double dfin = minv;
        if (tid == 0) {
            u_[cur] += dfin;
            for (int e = 0; e < Lns; ++e) {
                int j = sc_j[e];
                u_[row4col_[j]] += dfin - shortest_[j];   // col4row[i2]==j pre-augment
                v_[j] -= dfin - shortest_[j];             // sink term is exactly 0, skipped
            }
            // augment along alternating path
            int j = fj;
            while (true) {
                int i2 = path_[j];
                row4col_[j] = (short)i2;
                int nj = col4row_[i2];
                col4row_[i2] = (short)j;
                j = nj;
                if (i2 == cur) break;
            }
        }
        __syncthreads();   // tid0 updates drained before next row's shortest_ re-init
    }

    // outputs (transposed case): order = argsort(col4row);
    // row_ind = col4row[order]; col_ind = order. Values distinct -> rank by
    // counting smaller values (static bound -> unrolled, pipelined).
    if (tid < NTGT) {
        int val = col4row_[tid];
        int rank = 0;
        #pragma unroll
        for (int k = 0; k < NTGT; ++k) rank += (col4row_[k] < val);
        row_out[b * NTGT + rank] = (float)val;
        col_out[b * NTGT + rank] = (float)tid;
    }
}

extern "C" void kernel_launch(void* const* d_in, const int* in_sizes, int n_in,
                              void* d_out, int out_size, void* d_ws, size_t ws_size,
                              hipStream_t stream) {
    const float* outputs = (const float*)d_in[0];   // [16, 4096, 4]
    const float* targets = (const float*)d_in[1];   // [16, 128, 4]
    float* out = (float*)d_out;                     // C | row_ind | col_ind (as f32)

    u64* rowkey2 = (u64*)d_ws;                      // NB*NBLK*NTGT*8 = 2 MB

    hipLaunchKernelGGL(cost_kernel, dim3(CELEMS / 16 / 256), dim3(256), 0, stream,
                       outputs, targets, out, rowkey2);
    hipLaunchKernelGGL(lsa_kernel, dim3(NB), dim3(BT), 0, stream,
                       outputs, targets, rowkey2,
                       out + CELEMS, out + CELEMS + NB * NTGT);
}

// Round 9
// 51.092 us; speedup vs baseline: 1.1682x; 1.1682x over previous
//
#include <hip/hip_runtime.h>
#include <math.h>

#define NB   16
#define NQ   4096
#define NTGT 128
#define CELEMS (NB * NQ * NTGT)

#define BT  512
#define NW  (BT / 64)
#define CPT 8              // columns per thread in lsa (NQ / BT), strided ownership
#define NBLK 128           // cost blocks per batch == rowkey slots per batch

typedef unsigned long long u64;

// ---------------- cost matrix + per-row (target) min/argmin ----------------
// Grid 2048 x 256. Each thread handles 4 q's x 4 t's (16 cells); float4 loads
// and stores fully coalesced. Block covers 32 q x 128 t; per-row key
// (cost_bits<<32 | q, u64-min == min cost then lowest q) is reduced in LDS,
// then PLAIN-stored to the block's own slot rowkey2[b][blk][t].
__global__ __launch_bounds__(256) void cost_kernel(
    const float* __restrict__ outputs,
    const float* __restrict__ targets,
    float* __restrict__ C,
    u64*   __restrict__ rowkey2)      // [NB][NBLK][NTGT]
{
    __shared__ u64 part[8][NTGT];     // 8 KB
    const int tid  = threadIdx.x;
    const int idx0 = blockIdx.x * 1024 + tid;    // quad-cell base
    const int t4   = tid & 31;
    const int qloc = tid >> 5;
    const int b    = blockIdx.x >> 7;            // 128 blocks per batch
    const int blk  = blockIdx.x & (NBLK - 1);

    const float4* tg = reinterpret_cast<const float4*>(targets) + (b << 7) + (t4 << 2);
    float4 g[4];
    #pragma unroll
    for (int f = 0; f < 4; ++f) g[f] = tg[f];

    u64 keymin[4] = {~0ull, ~0ull, ~0ull, ~0ull};

    #pragma unroll
    for (int e = 0; e < 4; ++e) {
        int idx = idx0 + 256 * e;
        int bq  = idx >> 5;
        float4 o = reinterpret_cast<const float4*>(outputs)[bq];
        u64 q = (u64)(unsigned)(bq & (NQ - 1));
        float r[4];
        #pragma unroll
        for (int f = 0; f < 4; ++f) {
            float4 gg = g[f];
            r[f] = (fabsf(o.x - gg.x) + fabsf(o.y - gg.y)) +
                   (fabsf(o.z - gg.z) + fabsf(o.w - gg.w));
            u64 key = (((u64)__float_as_uint(r[f])) << 32) | q;
            if (key < keymin[f]) keymin[f] = key;
        }
        reinterpret_cast<float4*>(C)[idx] = make_float4(r[0], r[1], r[2], r[3]);
    }

    #pragma unroll
    for (int f = 0; f < 4; ++f) part[qloc][(t4 << 2) + f] = keymin[f];
    __syncthreads();

    if (tid < NTGT) {
        u64 k = part[0][tid];
        #pragma unroll
        for (int qq = 1; qq < 8; ++qq) { u64 ov = part[qq][tid]; if (ov < k) k = ov; }
        rowkey2[(((size_t)b * NBLK) + blk) * NTGT + tid] = k;
    }
}

// ---------------- LSA kernel: row-reduction init + rare augmentation ----------
// One block per batch, transposed problem: 128 rows (targets) x 4096 cols
// (queries). u[i] = rowmin[i], v = 0 (dual feasible); greedy claim of tight
// edges; leftover rows run exact f64 shortest-augmenting-path from these
// duals -> provably optimal matching (unique optimum for random floats ->
// identical indices to scipy). Column state in LDS, strided ownership
// (thread t owns columns t, t+512, ...). Scan is BRANCHLESS: all LDS loads
// unconditional (latency-overlapped); `rem` only masks compare/update.
// One barrier per Dijkstra iteration (parity-buffered reduce slots).
__global__ __launch_bounds__(BT, 1) void lsa_kernel(
    const float* __restrict__ outputs,
    const float* __restrict__ targets,
    const u64*   __restrict__ rowkey2,
    float* __restrict__ row_out,   // [NB, NTGT] as float
    float* __restrict__ col_out)   // [NB, NTGT] as float
{
    __shared__ float4 out_lds[NQ];          // 64 KB
    __shared__ double v_[NQ];               // 32 KB
    __shared__ double shortest_[NQ];        // 32 KB (aliased as u32 claim[] pre-Dijkstra)
    __shared__ short  row4col_[NQ];         // 8 KB
    __shared__ unsigned char path_[NQ];     // 4 KB
    __shared__ float4 tgt_[NTGT];           // 2 KB
    __shared__ double u_[NTGT];             // 1 KB
    __shared__ u64    red2_[4][NTGT];       // 4 KB
    __shared__ int    rowarg_[NTGT];
    __shared__ short  col4row_[NTGT];
    __shared__ short  left_[NTGT];
    __shared__ int    sc_j[NTGT];
    __shared__ double red_val[2][NW];
    __shared__ int    red_idx[2][NW];
    __shared__ u64    bmask[2];
    __shared__ int    nleft_;

    const int tid = threadIdx.x;
    const int b   = blockIdx.x;
    const float4* outq = reinterpret_cast<const float4*>(outputs) + b * NQ;
    unsigned* claim = (unsigned*)shortest_;   // dead storage during claim phase

    // init column state + stage outputs into LDS (coalesced)
    #pragma unroll
    for (int kk = 0; kk < CPT; ++kk) {
        int k = tid + BT * kk;
        out_lds[k] = outq[k];
        v_[k] = 0.0;
        row4col_[k] = -1;
        claim[k] = 0xFFFFFFFFu;
    }

    // reduce the 128 slot keys per row (coalesced: consecutive lanes -> consecutive t)
    {
        const int t = tid & 127, s = tid >> 7;            // 4 slices x 32 slots
        const u64* rk = rowkey2 + (size_t)b * NBLK * NTGT;
        u64 k = ~0ull;
        #pragma unroll
        for (int gg = 0; gg < NBLK / 4; ++gg) {
            u64 ov = rk[(s * (NBLK / 4) + gg) * NTGT + t];
            if (ov < k) k = ov;
        }
        red2_[s][t] = k;
    }
    __syncthreads();

    if (tid < NTGT) {
        u64 key = red2_[0][tid];
        #pragma unroll
        for (int s = 1; s < 4; ++s) { u64 ov = red2_[s][tid]; if (ov < key) key = ov; }
        u_[tid] = (double)__uint_as_float((unsigned)(key >> 32));
        rowarg_[tid] = (int)(key & 0xffffffffu);
        tgt_[tid] = reinterpret_cast<const float4*>(targets)[b * NTGT + tid];
    }
    __syncthreads();

    // greedy claim of tight edges: lowest row wins each contested column
    if (tid < NTGT) atomicMin(&claim[rowarg_[tid]], (unsigned)tid);
    __syncthreads();

    bool un = false;
    if (tid < NTGT) {
        int j = rowarg_[tid];
        bool won = (claim[j] == (unsigned)tid);
        col4row_[tid] = won ? (short)j : (short)-1;
        if (won) row4col_[j] = (short)tid;   // winners have distinct j
        un = !won;
    }
    // ballot-compact the unmatched rows (ascending tid order)
    {
        u64 m = __ballot(un);
        if ((tid & 63) == 0 && (tid >> 6) < 2) bmask[tid >> 6] = m;
    }
    __syncthreads();
    if (un) {
        int lane = tid & 63, w = tid >> 6;
        int r = __popcll(bmask[w] & ((1ull << lane) - 1)) + (w ? __popcll(bmask[0]) : 0);
        left_[r] = (short)tid;
    }
    if (tid == 0) nleft_ = __popcll(bmask[0]) + __popcll(bmask[1]);
    __syncthreads();
    const int nleft = nleft_;
    int parity = 0;

    // ---- exact shortest-augmenting-path for leftover rows ----
    for (int li = 0; li < nleft; ++li) {
        const int cur = left_[li];
        // re-init shortest_ (own columns only; no barrier needed before scan)
        #pragma unroll
        for (int kk = 0; kk < CPT; ++kk) shortest_[tid + BT * kk] = (double)INFINITY;
        unsigned rem  = 0xFFu;
        int    i      = cur;
        double minv   = 0.0;
        int    fj     = -1;
        int    Lns    = 0;

        while (true) {
            const double ui = u_[i];
            const float4 g  = tgt_[i];

            double bv = (double)INFINITY;
            int    bi = 0x7fffffff;

            // branchless scan: unconditional loads, masked compare/update
            #pragma unroll
            for (int kk = 0; kk < CPT; ++kk) {
                int k = tid + BT * kk;
                float4 oo = out_lds[k];
                float  c  = (fabsf(oo.x - g.x) + fabsf(oo.y - g.y)) +
                            (fabsf(oo.z - g.z) + fabsf(oo.w - g.w));
                double cand = ((minv + (double)c) - ui) - v_[k];
                double sold = shortest_[k];
                bool valid  = (rem >> kk) & 1u;
                bool upd    = valid && (cand < sold);
                if (upd) { shortest_[k] = cand; path_[k] = (unsigned char)i; }
                double s = upd ? cand : sold;
                if (valid && s < bv) { bv = s; bi = k; }
            }

            // wave reduce with explicit (value, lowest-index) tie-break
            for (int off = 32; off > 0; off >>= 1) {
                double ov = __shfl_down(bv, off);
                int    oi = __shfl_down(bi, off);
                if (ov < bv || (ov == bv && oi < bi)) { bv = ov; bi = oi; }
            }
            if ((tid & 63) == 0) { red_val[parity][tid >> 6] = bv; red_idx[parity][tid >> 6] = bi; }
            __syncthreads();

            double fv = red_val[parity][0];
            int    jj = red_idx[parity][0];
            #pragma unroll
            for (int w = 1; w < NW; ++w) {
                double ov = red_val[parity][w];
                int    oi = red_idx[parity][w];
                if (ov < fv || (ov == fv && oi < jj)) { fv = ov; jj = oi; }
            }
            parity ^= 1;           // next iteration uses the other slots: no 2nd barrier

            fj   = jj;
            minv = fv;

            if ((fj & (BT - 1)) == tid) rem &= ~(1u << (fj >> 9));   // owner drops it

            int r = row4col_[fj];
            if (r < 0) break;                 // sink found
            if (tid == 0) sc_j[Lns] = fj;
            Lns++;
            i = r;
        }

        // ---- row end: duals + augment (tid0; reference op order) ----
        const double dfin = minv;
        if (tid == 0) {
            u_[cur] += dfin;
            for (int e = 0; e < Lns; ++e) {
                int j = sc_j[e];
                u_[row4col_[j]] += dfin - shortest_[j];   // row4col pre-augment
                v_[j] -= dfin - shortest_[j];             // sink term exactly 0, skipped
            }
            // augment along alternating path
            int j = fj;
            while (true) {
                int i2 = path_[j];
                row4col_[j] = (short)i2;
                int nj = col4row_[i2];
                col4row_[i2] = (short)j;
                j = nj;
                if (i2 == cur) break;
            }
        }
        __syncthreads();   // publish tid0's updates before next row's scan
    }

    // outputs (transposed case): order = argsort(col4row);
    // row_ind = col4row[order]; col_ind = order. Values distinct -> rank by
    // counting smaller values.
    if (tid < NTGT) {
        int val = col4row_[tid];
        int rank = 0;
        #pragma unroll
        for (int k = 0; k < NTGT; ++k) rank += (col4row_[k] < val);
        row_out[b * NTGT + rank] = (float)val;
        col_out[b * NTGT + rank] = (float)tid;
    }
}

extern "C" void kernel_launch(void* const* d_in, const int* in_sizes, int n_in,
                              void* d_out, int out_size, void* d_ws, size_t ws_size,
                              hipStream_t stream) {
    const float* outputs = (const float*)d_in[0];   // [16, 4096, 4]
    const float* targets = (const float*)d_in[1];   // [16, 128, 4]
    float* out = (float*)d_out;                     // C | row_ind | col_ind (as f32)

    u64* rowkey2 = (u64*)d_ws;                      // NB*NBLK*NTGT*8 = 2 MB

    hipLaunchKernelGGL(cost_kernel, dim3(CELEMS / 16 / 256), dim3(256), 0, stream,
                       outputs, targets, out, rowkey2);
    hipLaunchKernelGGL(lsa_kernel, dim3(NB), dim3(BT), 0, stream,
                       outputs, targets, rowkey2,
                       out + CELEMS, out + CELEMS + NB * NTGT);
}